// Round 18
// baseline (110.450 us; speedup 1.0000x reference)
//
#include <hip/hip_runtime.h>
#include <stdint.h>

#define DIM 64
#define NE 2048
#define NROWS 65536
#define HW 4096

#define DECAYF 0.99f
#define OMDF ((float)(1.0 - 0.99))
#define EPSF 1e-5f
#define NEPSF ((float)(2048.0 * 1e-5))

typedef _Float16 f16x8 __attribute__((ext_vector_type(8)));
typedef float f32x4 __attribute__((ext_vector_type(4)));

#define SPLIT_SCALE 1024.0f
#define SPLIT_INV 0.0009765625f   // 2^-10

// -- prep: epack (blocks 0-63) + se (64-71) + n_pre (72), E read once ----
// n = sum(new_cluster_size) = 0.99*sum(cs_in) + 0.01*sum(counts), and
// sum(counts) == NROWS identically -> closed form, kills the single-block
// finalize_a launch. Perturbation vs reference's sum order ~1e-4 abs on
// n~655 -> ~5e-9 relative on new_embed. cs_in is all zeros in practice.
__global__ __launch_bounds__(256) void prep_kernel(const float* __restrict__ E,
                                                   const float* __restrict__ cs_in,
                                                   _Float16* __restrict__ Eh,
                                                   _Float16* __restrict__ El,
                                                   float* __restrict__ se,
                                                   float* __restrict__ n_pre) {
  const int bid = blockIdx.x;
  const int tid = threadIdx.x;
  if (bid < 64) {
    int task = bid * 256 + tid;  // 16384 = 128 tiles * 2 ks * 64 lanes
    int l = task & 63;
    int ks = (task >> 6) & 1;
    int t = task >> 7;
    int j = t * 16 + (l & 15);
    int d0 = ks * 32 + ((l >> 4) & 3) * 8;
    _Float16 h8[8], l8[8];
#pragma unroll
    for (int r = 0; r < 8; ++r) {
      float v = E[(d0 + r) * NE + j];
      _Float16 h = (_Float16)v;
      h8[r] = h;
      l8[r] = (_Float16)((v - (float)h) * SPLIT_SCALE);
    }
    *(f16x8*)(Eh + (size_t)task * 8) = *(f16x8*)h8;
    *(f16x8*)(El + (size_t)task * 8) = *(f16x8*)l8;
  } else if (bid < 72) {
    int j = (bid - 64) * 256 + tid;
    float s = 0.f;
#pragma unroll
    for (int d = 0; d < DIM; ++d) {
      float v = E[d * NE + j];
      s += v * v;
    }
    se[j] = s;
  } else {
    float local = 0.f;
#pragma unroll
    for (int u = 0; u < 8; ++u) local += cs_in[u * 256 + tid];
#pragma unroll
    for (int off = 32; off > 0; off >>= 1) local += __shfl_down(local, off, 64);
    __shared__ float red[4];
    if ((tid & 63) == 0) red[tid >> 6] = local;
    __syncthreads();
    if (tid == 0) {
      float s = (red[0] + red[1]) + (red[2] + red[3]);
      *n_pre = DECAYF * s + OMDF * (float)NROWS;
    }
  }
}

// ---------------- argmin: r12 structure verbatim (proven 74.5us) --------
// Local optimum confirmed from 4 directions: r13 (rows/wave x2 -> 93us),
// r14 (code-partitioned waves -> 85us), r16 (4-deep prefetch, VGPR 132
// crosses the 128 step -> 97us), r5/r6 (512-thr -> 128-VGPR cap, spills).
// 2-tile ping-pong at VGPR 64, 2 waves/SIMD. Macro locals acc1/acc2
// (r15's shadowing bug: locals named a1/a2 captured outer buffers).
#define MFMA16(A, B, C) __builtin_amdgcn_mfma_f32_16x16x32_f16(A, B, C, 0, 0, 0)

#define COMPUTE_TILE(T, B0, B1, B2, B3, SEJ)                              \
  {                                                                       \
    _Pragma("unroll") for (int rt = 0; rt < 2; ++rt) {                    \
      f32x4 acc1 = {0.f, 0.f, 0.f, 0.f};                                  \
      f32x4 acc2 = {0.f, 0.f, 0.f, 0.f};                                  \
      acc1 = MFMA16(xh[rt][0], B0, acc1);                                 \
      acc1 = MFMA16(xh[rt][1], B1, acc1);                                 \
      acc2 = MFMA16(xh[rt][0], B2, acc2);                                 \
      acc2 = MFMA16(xh[rt][1], B3, acc2);                                 \
      acc2 = MFMA16(xl[rt][0], B0, acc2);                                 \
      acc2 = MFMA16(xl[rt][1], B1, acc2);                                 \
      _Pragma("unroll") for (int q = 0; q < 4; ++q) {                     \
        float dot = fmaf(acc2[q], SPLIT_INV, acc1[q]);                    \
        float dist = fmaf(-2.f, dot, SEJ);                                \
        if (dist < bv[rt][q]) { bv[rt][q] = dist; bi[rt][q] = (T)*16 + lc; } \
      }                                                                   \
    }                                                                     \
  }

__global__ __launch_bounds__(256) void argmin_mfma_kernel(
    const float* __restrict__ x, const _Float16* __restrict__ Eh,
    const _Float16* __restrict__ El, const float* __restrict__ se,
    int* __restrict__ ind, float* __restrict__ ind_f) {
  const int tid = threadIdx.x;
  const int lane = tid & 63;
  const int wv = tid >> 6;
  const int R0 = blockIdx.x * 128 + wv * 32;
  const int lg = (lane >> 4) & 3;   // k-group / D-row group
  const int lc = lane & 15;         // A-row / B-col / D-col

  // A-fragments: xh, xl' for 2 row-tiles x 2 ksteps
  f16x8 xh[2][2], xl[2][2];
#pragma unroll
  for (int rt = 0; rt < 2; ++rt) {
#pragma unroll
    for (int ks = 0; ks < 2; ++ks) {
      int r_glob = R0 + rt * 16 + lc;
      const float* xr = x + (size_t)(r_glob >> 12) * (DIM * HW) + (r_glob & 4095);
      int d0 = ks * 32 + lg * 8;
      _Float16 h8[8], l8[8];
#pragma unroll
      for (int e = 0; e < 8; ++e) {
        float v = xr[(d0 + e) * HW];
        _Float16 h = (_Float16)v;
        h8[e] = h;
        l8[e] = (_Float16)((v - (float)h) * SPLIT_SCALE);
      }
      xh[rt][ks] = *(f16x8*)h8;
      xl[rt][ks] = *(f16x8*)l8;
    }
  }

  float bv[2][4];
  int bi[2][4];
#pragma unroll
  for (int rt = 0; rt < 2; ++rt)
#pragma unroll
    for (int q = 0; q < 4; ++q) { bv[rt][q] = 3.4e38f; bi[rt][q] = 0; }

  const size_t lo = (size_t)lane * 8;
  // current buffer <- tile 0
  f16x8 c0 = *(const f16x8*)(Eh + lo);
  f16x8 c1 = *(const f16x8*)(Eh + 512 + lo);
  f16x8 c2 = *(const f16x8*)(El + lo);
  f16x8 c3 = *(const f16x8*)(El + 512 + lo);
  float seC = se[lc];

  for (int t = 0; t < NE / 16; t += 2) {
    // prefetch tile t+1 (always exists: 128 tiles, t even)
    f16x8 n0 = *(const f16x8*)(Eh + (size_t)(t + 1) * 1024 + lo);
    f16x8 n1 = *(const f16x8*)(Eh + (size_t)(t + 1) * 1024 + 512 + lo);
    f16x8 n2 = *(const f16x8*)(El + (size_t)(t + 1) * 1024 + lo);
    f16x8 n3 = *(const f16x8*)(El + (size_t)(t + 1) * 1024 + 512 + lo);
    float seN = se[(t + 1) * 16 + lc];

    COMPUTE_TILE(t, c0, c1, c2, c3, seC);

    if (t + 2 < NE / 16) {   // prefetch tile t+2
      c0 = *(const f16x8*)(Eh + (size_t)(t + 2) * 1024 + lo);
      c1 = *(const f16x8*)(Eh + (size_t)(t + 2) * 1024 + 512 + lo);
      c2 = *(const f16x8*)(El + (size_t)(t + 2) * 1024 + lo);
      c3 = *(const f16x8*)(El + (size_t)(t + 2) * 1024 + 512 + lo);
      seC = se[(t + 2) * 16 + lc];
    }

    COMPUTE_TILE(t + 1, n0, n1, n2, n3, seN);
  }

  // reduce over the 16 lanes (lc) holding different column classes
#pragma unroll
  for (int rt = 0; rt < 2; ++rt) {
#pragma unroll
    for (int q = 0; q < 4; ++q) {
      float v = bv[rt][q];
      int ix = bi[rt][q];
#pragma unroll
      for (int off = 1; off < 16; off <<= 1) {
        float ov = __shfl_xor(v, off, 64);
        int oi = __shfl_xor(ix, off, 64);
        if (ov < v || (ov == v && oi < ix)) { v = ov; ix = oi; }
      }
      if (lc == 0) {
        int grow = R0 + rt * 16 + lg * 4 + q;   // D-row = (lane>>4)*4 + q
        ind[grow] = ix;
        ind_f[grow] = (float)ix;
      }
    }
  }
}

// ---- fused: out + diff + esum/counts, nbg batch-groups (runtime) -------
// grid = 64*nbg; 8 bgs -> 512 blocks = 2/CU (was 1/CU at 4 bgs). LDS
// 40KB x 2 blocks = 80KB <= 160KB.
__global__ __launch_bounds__(256) void esum_fused_kernel(const float* __restrict__ x,
                                                         const float* __restrict__ E,
                                                         const int* __restrict__ ind,
                                                         float* __restrict__ out,
                                                         float* __restrict__ diff_acc,
                                                         float* __restrict__ pesum,
                                                         int* __restrict__ pcnt,
                                                         int nbg) {
  const int bg = blockIdx.x % nbg;
  const int d = blockIdx.x / nbg;
  const int nb = 16 / nbg;
  __shared__ float h[4][NE];   // 32 KB
  __shared__ int cnt[NE];      // 8 KB
  const int tid = threadIdx.x;
  const int w = tid >> 6;
  float* hf = &h[0][0];
#pragma unroll
  for (int u = 0; u < 32; ++u) hf[u * 256 + tid] = 0.f;
  if (d == 0) {
#pragma unroll
    for (int u = 0; u < 8; ++u) cnt[u * 256 + tid] = 0;
  }
  __syncthreads();
  const float* Ed = E + d * NE;
  float local = 0.f;
  for (int b = bg * nb; b < bg * nb + nb; ++b) {
    const int* ib = ind + b * 4096;
    const float* xb = x + ((size_t)b * DIM + d) * 4096;
    float* ob = out + ((size_t)b * DIM + d) * 4096;
#pragma unroll 4
    for (int it = 0; it < 16; ++it) {
      int i = it * 256 + tid;
      int idx = ib[i];
      float xv = xb[i];
      float qv = Ed[idx];
      float dq = qv - xv;
      ob[i] = xv + dq;          // replicate xp + (quantize - xp)
      local += dq * dq;
      atomicAdd(&h[w][idx], xv);
      if (d == 0) atomicAdd(&cnt[idx], 1);
    }
  }
#pragma unroll
  for (int off = 32; off > 0; off >>= 1) local += __shfl_down(local, off, 64);
  __shared__ float wsum[4];
  if ((tid & 63) == 0) wsum[tid >> 6] = local;
  __syncthreads();
  if (tid == 0) {
    float s = (wsum[0] + wsum[1]) + (wsum[2] + wsum[3]);
    atomicAdd(diff_acc, s * (1.f / 4194304.f));
  }
  float* pe = pesum + ((size_t)bg * DIM + d) * NE;
#pragma unroll
  for (int u = 0; u < 8; ++u) {
    int j = u * 256 + tid;
    pe[j] = (h[0][j] + h[1][j]) + (h[2][j] + h[3][j]);
  }
  if (d == 0) {
    int* pc = pcnt + bg * NE;
#pragma unroll
    for (int u = 0; u < 8; ++u) {
      int j = u * 256 + tid;
      pc[j] = cnt[j];
    }
  }
}

// ---- fused finalize: ncs + new_embed_avg + new_embed, one launch -------
// Each thread recomputes its code's ncs from the count partials (cheap);
// k<2048 threads also store new_cluster_size. n from prep's closed form.
__global__ __launch_bounds__(256) void finalize_fused(const float* __restrict__ ea_in,
                                                      const float* __restrict__ cs_in,
                                                      const float* __restrict__ pesum,
                                                      const int* __restrict__ pcnt,
                                                      const float* __restrict__ n_pre,
                                                      float* __restrict__ nea_slot,
                                                      float* __restrict__ ncs_slot,
                                                      float* __restrict__ ne_slot,
                                                      int nbg) {
  const int k = blockIdx.x * 256 + threadIdx.x;  // 131072
  const int kk = k & (NE - 1);
  const size_t P = (size_t)DIM * NE;
  float es = 0.f;
  int c = 0;
  for (int g = 0; g < nbg; ++g) {
    es += pesum[(size_t)g * P + k];
    c += pcnt[g * NE + kk];
  }
  const float n = *n_pre;
  float nea = DECAYF * ea_in[k] + OMDF * es;
  nea_slot[k] = nea;
  float ncs = DECAYF * cs_in[kk] + OMDF * (float)c;
  if (k < NE) ncs_slot[k] = ncs;
  float cs = (ncs + EPSF) / (n + NEPSF) * n;
  ne_slot[k] = nea / cs;
}

// ================= small-workspace fallback path (r10, proven) ==========
#define BRF 128
#define TCF 128
#define NTF (NE / TCF)
__global__ __launch_bounds__(256, 2) void argmin_lds_kernel(const float* __restrict__ x,
                                                            const float* __restrict__ E,
                                                            const float* __restrict__ se,
                                                            int* __restrict__ ind,
                                                            float* __restrict__ ind_f) {
  __shared__ float Xs[DIM][BRF];
  __shared__ float Es[DIM][TCF];
  const int tid = threadIdx.x;
  const int rg = tid >> 4;
  const int cg = tid & 15;
  const int B0 = blockIdx.x * BRF;
  const float* xb = x + (size_t)(B0 >> 12) * (DIM * HW) + (B0 & 4095);
  float* Xf = &Xs[0][0];
#pragma unroll
  for (int k = 0; k < 8; ++k) {
    int i = k * 1024 + tid * 4;
    *(float4*)(Xf + i) = *(const float4*)(xb + (i >> 7) * HW + (i & 127));
  }
  float bv[8];
  int bi[8];
#pragma unroll
  for (int i2 = 0; i2 < 8; ++i2) { bv[i2] = 3.4e38f; bi[i2] = 0; }
  float* Ef = &Es[0][0];
  for (int t = 0; t < NTF; ++t) {
    __syncthreads();
#pragma unroll
    for (int k = 0; k < 8; ++k) {
      int i = k * 1024 + tid * 4;
      *(float4*)(Ef + i) = *(const float4*)(E + (i >> 7) * NE + t * TCF + (i & 127));
    }
    __syncthreads();
    float acc[8][8];
#pragma unroll
    for (int i2 = 0; i2 < 8; ++i2)
#pragma unroll
      for (int j = 0; j < 8; ++j) acc[i2][j] = 0.f;
#pragma unroll 8
    for (int d = 0; d < DIM; ++d) {
      float4 xa = *(const float4*)&Xs[d][rg * 8];
      float4 xc = *(const float4*)&Xs[d][rg * 8 + 4];
      float4 ea = *(const float4*)&Es[d][cg * 4];
      float4 ec = *(const float4*)&Es[d][cg * 4 + 64];
      float xr[8] = {xa.x, xa.y, xa.z, xa.w, xc.x, xc.y, xc.z, xc.w};
      float er[8] = {ea.x, ea.y, ea.z, ea.w, ec.x, ec.y, ec.z, ec.w};
#pragma unroll
      for (int i2 = 0; i2 < 8; ++i2)
#pragma unroll
        for (int j = 0; j < 8; ++j) acc[i2][j] = fmaf(xr[i2], er[j], acc[i2][j]);
    }
    float4 s0 = *(const float4*)(se + t * TCF + cg * 4);
    float4 s1 = *(const float4*)(se + t * TCF + cg * 4 + 64);
    float sv[8] = {s0.x, s0.y, s0.z, s0.w, s1.x, s1.y, s1.z, s1.w};
#pragma unroll
    for (int i2 = 0; i2 < 8; ++i2) {
#pragma unroll
      for (int j = 0; j < 8; ++j) {
        float dist = fmaf(-2.f, acc[i2][j], sv[j]);
        if (dist < bv[i2]) {
          bv[i2] = dist;
          bi[i2] = t * TCF + (j >> 2) * 64 + cg * 4 + (j & 3);
        }
      }
    }
  }
#pragma unroll
  for (int i2 = 0; i2 < 8; ++i2) {
    float v = bv[i2];
    int ix = bi[i2];
#pragma unroll
    for (int off = 1; off < 16; off <<= 1) {
      float ov = __shfl_xor(v, off, 64);
      int oi = __shfl_xor(ix, off, 64);
      if (ov < v || (ov == v && oi < ix)) { v = ov; ix = oi; }
    }
    bv[i2] = v;
    bi[i2] = ix;
  }
  if (cg == 0) {
#pragma unroll
    for (int i2 = 0; i2 < 8; ++i2) {
      int grow = B0 + rg * 8 + i2;
      ind[grow] = bi[i2];
      ind_f[grow] = (float)bi[i2];
    }
  }
}

__global__ __launch_bounds__(256) void outdiff_kernel(const float* __restrict__ x,
                                                      const float* __restrict__ E,
                                                      const int* __restrict__ ind,
                                                      float* __restrict__ out,
                                                      float* __restrict__ diff_acc) {
  const int t = threadIdx.x;
  float local = 0.f;
  const int base = blockIdx.x * 1024;
#pragma unroll
  for (int u = 0; u < 4; ++u) {
    int i = base + u * 256 + t;
    int hw = i & 4095;
    int bc = i >> 12;
    int c = bc & 63;
    int b = bc >> 6;
    int idx = ind[b * 4096 + hw];
    float xv = x[i];
    float qv = E[c * NE + idx];
    float dq = qv - xv;
    out[i] = xv + dq;
    local += dq * dq;
  }
#pragma unroll
  for (int off = 32; off > 0; off >>= 1) local += __shfl_down(local, off, 64);
  __shared__ float wsum[4];
  if ((t & 63) == 0) wsum[t >> 6] = local;
  __syncthreads();
  if (t == 0) {
    float s = wsum[0] + wsum[1] + wsum[2] + wsum[3];
    atomicAdd(diff_acc, s * (1.f / 4194304.f));
  }
}

__global__ __launch_bounds__(256) void scatter_atomic_kernel(const float* __restrict__ x,
                                                             const int* __restrict__ ind,
                                                             float* __restrict__ counts,
                                                             float* __restrict__ esum) {
  const int row = blockIdx.x * 256 + threadIdx.x;
  const int idx = ind[row];
  atomicAdd(&counts[idx], 1.f);
  const int b = row >> 12;
  const int hw = row & 4095;
  const float* xr = x + (size_t)b * (DIM * HW) + hw;
#pragma unroll
  for (int d = 0; d < DIM; ++d) atomicAdd(&esum[d * NE + idx], xr[d * HW]);
}

__global__ __launch_bounds__(1024) void finalize_a_float(const float* __restrict__ cs_in,
                                                         float* __restrict__ ncs_slot,
                                                         float* __restrict__ n_out) {
  const int t = threadIdx.x;
  float local = 0.f;
#pragma unroll
  for (int u = 0; u < 2; ++u) {
    int k = u * 1024 + t;
    float v = DECAYF * cs_in[k] + OMDF * ncs_slot[k];
    ncs_slot[k] = v;
    local += v;
  }
#pragma unroll
  for (int off = 32; off > 0; off >>= 1) local += __shfl_down(local, off, 64);
  __shared__ float red[16];
  if ((t & 63) == 0) red[t >> 6] = local;
  __syncthreads();
  if (t == 0) {
    float s = 0.f;
#pragma unroll
    for (int k = 0; k < 16; ++k) s += red[k];
    *n_out = s;
  }
}

__global__ __launch_bounds__(256) void finalize_b_inplace(const float* __restrict__ ea_in,
                                                          float* __restrict__ nea_slot,
                                                          const float* __restrict__ ncs_slot,
                                                          const float* __restrict__ n_out,
                                                          float* __restrict__ ne_slot) {
  const int k = blockIdx.x * 256 + threadIdx.x;
  const float n = *n_out;
  float nea = DECAYF * ea_in[k] + OMDF * nea_slot[k];
  nea_slot[k] = nea;
  float ncs = ncs_slot[k & (NE - 1)];
  float cs = (ncs + EPSF) / (n + NEPSF) * n;
  ne_slot[k] = nea / cs;
}

extern "C" void kernel_launch(void* const* d_in, const int* in_sizes, int n_in,
                              void* d_out, int out_size, void* d_ws, size_t ws_size,
                              hipStream_t stream) {
  const float* x = (const float*)d_in[0];      // [16,64,64,64]
  const float* E = (const float*)d_in[1];      // [64,2048]
  const float* cs_in = (const float*)d_in[2];  // [2048]
  const float* ea_in = (const float*)d_in[3];  // [64,2048]
  float* out = (float*)d_out;

  const size_t O_OUT = 0;
  const size_t O_DIFF = 4194304;
  const size_t O_IND = 4194305;
  const size_t O_NE = 4259841;    // new_embed [64,2048]
  const size_t O_NCS = 4390913;   // new_cluster_size [2048]
  const size_t O_NEA = 4392961;   // new_embed_avg [64,2048]

  // workspace layout (tiered on nbg partial-buffer count)
  float* se = (float*)d_ws;                  // 2048
  int* ind = (int*)(se + NE);                // 65536
  float* n_out = (float*)(ind + NROWS);      // 1 (+3 pad)
  int* pcnt = (int*)(n_out + 4);             // nbg*2048
  const size_t P = (size_t)DIM * NE;
  const size_t head = 2048 + 65536 + 4;
  int nbg = 8;
  size_t need = (head + (size_t)nbg * NE + (size_t)nbg * P) * 4;
  if (ws_size < need) {
    nbg = 4;
    need = (head + (size_t)nbg * NE + (size_t)nbg * P) * 4;
  }
  const bool big_ws = ws_size >= need;
  float* pesum = (float*)(pcnt + nbg * NE);
  // Epk overlays pesum (dead until esum_fused writes it, after argmin)
  _Float16* Ehpk = (_Float16*)pesum;         // 131072 f16 = 256 KB
  _Float16* Elpk = Ehpk + P;                 // 131072 f16

  hipMemsetAsync(out + O_DIFF, 0, 4, stream);

  if (big_ws) {
    prep_kernel<<<73, 256, 0, stream>>>(E, cs_in, Ehpk, Elpk, se, n_out);
    argmin_mfma_kernel<<<NROWS / 128, 256, 0, stream>>>(x, Ehpk, Elpk, se, ind,
                                                        out + O_IND);
    esum_fused_kernel<<<DIM * nbg, 256, 0, stream>>>(x, E, ind, out + O_OUT,
                                                     out + O_DIFF, pesum, pcnt, nbg);
    finalize_fused<<<(int)(P / 256), 256, 0, stream>>>(ea_in, cs_in, pesum, pcnt,
                                                       n_out, out + O_NEA,
                                                       out + O_NCS, out + O_NE, nbg);
  } else {
    prep_kernel<<<73, 256, 0, stream>>>(E, cs_in, Ehpk, Elpk, se, n_out);  // se needed
    argmin_lds_kernel<<<NROWS / BRF, 256, 0, stream>>>(x, E, se, ind, out + O_IND);
    outdiff_kernel<<<4096, 256, 0, stream>>>(x, E, ind, out + O_OUT, out + O_DIFF);
    hipMemsetAsync(out + O_NCS, 0, NE * 4, stream);
    hipMemsetAsync(out + O_NEA, 0, (size_t)DIM * NE * 4, stream);
    scatter_atomic_kernel<<<NROWS / 256, 256, 0, stream>>>(x, ind, out + O_NCS,
                                                           out + O_NEA);
    finalize_a_float<<<1, 1024, 0, stream>>>(cs_in, out + O_NCS, n_out);
    finalize_b_inplace<<<DIM * NE / 256, 256, 0, stream>>>(ea_in, out + O_NEA,
                                                           out + O_NCS, n_out,
                                                           out + O_NE);
  }
}

// Round 19
// 103.878 us; speedup vs baseline: 1.0633x; 1.0633x over previous
//
#include <hip/hip_runtime.h>
#include <stdint.h>

#define DIM 64
#define NE 2048
#define NROWS 65536
#define HW 4096

#define DECAYF 0.99f
#define OMDF ((float)(1.0 - 0.99))
#define EPSF 1e-5f
#define NEPSF ((float)(2048.0 * 1e-5))

typedef _Float16 f16x8 __attribute__((ext_vector_type(8)));
typedef float f32x4 __attribute__((ext_vector_type(4)));

#define SPLIT_SCALE 1024.0f
#define SPLIT_INV 0.0009765625f   // 2^-10

// ------ prep: epack (blocks 0-63) + se (blocks 64-71), E read once ------
__global__ __launch_bounds__(256) void prep_kernel(const float* __restrict__ E,
                                                   _Float16* __restrict__ Eh,
                                                   _Float16* __restrict__ El,
                                                   float* __restrict__ se) {
  const int bid = blockIdx.x;
  const int tid = threadIdx.x;
  if (bid < 64) {
    int task = bid * 256 + tid;  // 16384 = 128 tiles * 2 ks * 64 lanes
    int l = task & 63;
    int ks = (task >> 6) & 1;
    int t = task >> 7;
    int j = t * 16 + (l & 15);
    int d0 = ks * 32 + ((l >> 4) & 3) * 8;
    _Float16 h8[8], l8[8];
#pragma unroll
    for (int r = 0; r < 8; ++r) {
      float v = E[(d0 + r) * NE + j];
      _Float16 h = (_Float16)v;
      h8[r] = h;
      l8[r] = (_Float16)((v - (float)h) * SPLIT_SCALE);
    }
    *(f16x8*)(Eh + (size_t)task * 8) = *(f16x8*)h8;
    *(f16x8*)(El + (size_t)task * 8) = *(f16x8*)l8;
  } else {
    int j = (bid - 64) * 256 + tid;
    float s = 0.f;
#pragma unroll
    for (int d = 0; d < DIM; ++d) {
      float v = E[d * NE + j];
      s += v * v;
    }
    se[j] = s;
  }
}

// ---------------- argmin: r12/r17 structure + se-in-accumulator fold ----
// r17 (74.8us) local optimum confirmed from 4 directions (r13/r14/r16/
// r5-6 all regressed). This round's single change: acc1's MFMA C-operand
// is initialized to -se_j/2 (se depends only on the D-column = lane&15,
// so the per-lane broadcast init is exact for the 4 rows a lane holds);
// fold becomes argmax over val = fmaf(acc2, 2^-10, acc1) = -dist/2 -
// strictly monotone, so argmin/tie semantics preserved. Removes 1 fmaf
// per dist (1024/wave): VALU fold -20%.
#define MFMA16(A, B, C) __builtin_amdgcn_mfma_f32_16x16x32_f16(A, B, C, 0, 0, 0)

#define COMPUTE_TILE(T, B0, B1, B2, B3, SEJ2)                             \
  {                                                                       \
    _Pragma("unroll") for (int rt = 0; rt < 2; ++rt) {                    \
      f32x4 acc1 = {SEJ2, SEJ2, SEJ2, SEJ2};                              \
      f32x4 acc2 = {0.f, 0.f, 0.f, 0.f};                                  \
      acc1 = MFMA16(xh[rt][0], B0, acc1);                                 \
      acc1 = MFMA16(xh[rt][1], B1, acc1);                                 \
      acc2 = MFMA16(xh[rt][0], B2, acc2);                                 \
      acc2 = MFMA16(xh[rt][1], B3, acc2);                                 \
      acc2 = MFMA16(xl[rt][0], B0, acc2);                                 \
      acc2 = MFMA16(xl[rt][1], B1, acc2);                                 \
      _Pragma("unroll") for (int q = 0; q < 4; ++q) {                     \
        float val = fmaf(acc2[q], SPLIT_INV, acc1[q]);                    \
        if (val > bv[rt][q]) { bv[rt][q] = val; bi[rt][q] = (T)*16 + lc; } \
      }                                                                   \
    }                                                                     \
  }

__global__ __launch_bounds__(256) void argmin_mfma_kernel(
    const float* __restrict__ x, const _Float16* __restrict__ Eh,
    const _Float16* __restrict__ El, const float* __restrict__ se,
    int* __restrict__ ind, float* __restrict__ ind_f) {
  const int tid = threadIdx.x;
  const int lane = tid & 63;
  const int wv = tid >> 6;
  const int R0 = blockIdx.x * 128 + wv * 32;
  const int lg = (lane >> 4) & 3;   // k-group / D-row group
  const int lc = lane & 15;         // A-row / B-col / D-col

  // A-fragments: xh, xl' for 2 row-tiles x 2 ksteps
  f16x8 xh[2][2], xl[2][2];
#pragma unroll
  for (int rt = 0; rt < 2; ++rt) {
#pragma unroll
    for (int ks = 0; ks < 2; ++ks) {
      int r_glob = R0 + rt * 16 + lc;
      const float* xr = x + (size_t)(r_glob >> 12) * (DIM * HW) + (r_glob & 4095);
      int d0 = ks * 32 + lg * 8;
      _Float16 h8[8], l8[8];
#pragma unroll
      for (int e = 0; e < 8; ++e) {
        float v = xr[(d0 + e) * HW];
        _Float16 h = (_Float16)v;
        h8[e] = h;
        l8[e] = (_Float16)((v - (float)h) * SPLIT_SCALE);
      }
      xh[rt][ks] = *(f16x8*)h8;
      xl[rt][ks] = *(f16x8*)l8;
    }
  }

  float bv[2][4];
  int bi[2][4];
#pragma unroll
  for (int rt = 0; rt < 2; ++rt)
#pragma unroll
    for (int q = 0; q < 4; ++q) { bv[rt][q] = -3.4e38f; bi[rt][q] = 0; }

  const size_t lo = (size_t)lane * 8;
  // current buffer <- tile 0
  f16x8 c0 = *(const f16x8*)(Eh + lo);
  f16x8 c1 = *(const f16x8*)(Eh + 512 + lo);
  f16x8 c2 = *(const f16x8*)(El + lo);
  f16x8 c3 = *(const f16x8*)(El + 512 + lo);
  float seC = -0.5f * se[lc];

  for (int t = 0; t < NE / 16; t += 2) {
    // prefetch tile t+1 (always exists: 128 tiles, t even)
    f16x8 n0 = *(const f16x8*)(Eh + (size_t)(t + 1) * 1024 + lo);
    f16x8 n1 = *(const f16x8*)(Eh + (size_t)(t + 1) * 1024 + 512 + lo);
    f16x8 n2 = *(const f16x8*)(El + (size_t)(t + 1) * 1024 + lo);
    f16x8 n3 = *(const f16x8*)(El + (size_t)(t + 1) * 1024 + 512 + lo);
    float seN = -0.5f * se[(t + 1) * 16 + lc];

    COMPUTE_TILE(t, c0, c1, c2, c3, seC);

    if (t + 2 < NE / 16) {   // prefetch tile t+2
      c0 = *(const f16x8*)(Eh + (size_t)(t + 2) * 1024 + lo);
      c1 = *(const f16x8*)(Eh + (size_t)(t + 2) * 1024 + 512 + lo);
      c2 = *(const f16x8*)(El + (size_t)(t + 2) * 1024 + lo);
      c3 = *(const f16x8*)(El + (size_t)(t + 2) * 1024 + 512 + lo);
      seC = -0.5f * se[(t + 2) * 16 + lc];
    }

    COMPUTE_TILE(t + 1, n0, n1, n2, n3, seN);
  }

  // reduce over the 16 lanes (lc): max val, lowest index on ties
#pragma unroll
  for (int rt = 0; rt < 2; ++rt) {
#pragma unroll
    for (int q = 0; q < 4; ++q) {
      float v = bv[rt][q];
      int ix = bi[rt][q];
#pragma unroll
      for (int off = 1; off < 16; off <<= 1) {
        float ov = __shfl_xor(v, off, 64);
        int oi = __shfl_xor(ix, off, 64);
        if (ov > v || (ov == v && oi < ix)) { v = ov; ix = oi; }
      }
      if (lc == 0) {
        int grow = R0 + rt * 16 + lg * 4 + q;   // D-row = (lane>>4)*4 + q
        ind[grow] = ix;
        ind_f[grow] = (float)ix;
      }
    }
  }
}

// ---- fused: out (NCHW) + diff + esum/counts per-d-plane histograms -----
__global__ __launch_bounds__(256) void esum_fused_kernel(const float* __restrict__ x,
                                                         const float* __restrict__ E,
                                                         const int* __restrict__ ind,
                                                         float* __restrict__ out,
                                                         float* __restrict__ diff_acc,
                                                         float* __restrict__ pesum,
                                                         int* __restrict__ pcnt) {
  const int d = blockIdx.x >> 2;
  const int bg = blockIdx.x & 3;
  __shared__ float h[4][NE];   // 32 KB
  __shared__ int cnt[NE];      // 8 KB
  const int tid = threadIdx.x;
  const int w = tid >> 6;
  float* hf = &h[0][0];
#pragma unroll
  for (int u = 0; u < 32; ++u) hf[u * 256 + tid] = 0.f;
  if (d == 0) {
#pragma unroll
    for (int u = 0; u < 8; ++u) cnt[u * 256 + tid] = 0;
  }
  __syncthreads();
  const float* Ed = E + d * NE;
  float local = 0.f;
  for (int b = bg * 4; b < bg * 4 + 4; ++b) {
    const int* ib = ind + b * 4096;
    const float* xb = x + ((size_t)b * DIM + d) * 4096;
    float* ob = out + ((size_t)b * DIM + d) * 4096;
#pragma unroll 4
    for (int it = 0; it < 16; ++it) {
      int i = it * 256 + tid;
      int idx = ib[i];
      float xv = xb[i];
      float qv = Ed[idx];
      float dq = qv - xv;
      ob[i] = xv + dq;          // replicate xp + (quantize - xp)
      local += dq * dq;
      atomicAdd(&h[w][idx], xv);
      if (d == 0) atomicAdd(&cnt[idx], 1);
    }
  }
#pragma unroll
  for (int off = 32; off > 0; off >>= 1) local += __shfl_down(local, off, 64);
  __shared__ float wsum[4];
  if ((tid & 63) == 0) wsum[tid >> 6] = local;
  __syncthreads();
  if (tid == 0) {
    float s = (wsum[0] + wsum[1]) + (wsum[2] + wsum[3]);
    atomicAdd(diff_acc, s * (1.f / 4194304.f));
  }
  float* pe = pesum + ((size_t)bg * DIM + d) * NE;
#pragma unroll
  for (int u = 0; u < 8; ++u) {
    int j = u * 256 + tid;
    pe[j] = (h[0][j] + h[1][j]) + (h[2][j] + h[3][j]);
  }
  if (d == 0) {
    int* pc = pcnt + bg * NE;
#pragma unroll
    for (int u = 0; u < 8; ++u) {
      int j = u * 256 + tid;
      pc[j] = cnt[j];
    }
  }
}

// ---------------- finalize: new_cluster_size + n (partial counts) -------
__global__ __launch_bounds__(1024) void finalize_a4(const float* __restrict__ cs_in,
                                                    const int* __restrict__ pcnt,
                                                    float* __restrict__ ncs_slot,
                                                    float* __restrict__ n_out) {
  const int t = threadIdx.x;
  float local = 0.f;
#pragma unroll
  for (int u = 0; u < 2; ++u) {
    int k = u * 1024 + t;
    int c = (pcnt[k] + pcnt[NE + k]) + (pcnt[2 * NE + k] + pcnt[3 * NE + k]);
    float v = DECAYF * cs_in[k] + OMDF * (float)c;
    ncs_slot[k] = v;
    local += v;
  }
#pragma unroll
  for (int off = 32; off > 0; off >>= 1) local += __shfl_down(local, off, 64);
  __shared__ float red[16];
  if ((t & 63) == 0) red[t >> 6] = local;
  __syncthreads();
  if (t == 0) {
    float s = 0.f;
#pragma unroll
    for (int k = 0; k < 16; ++k) s += red[k];
    *n_out = s;
  }
}

// ---------------- finalize: new_embed_avg + new_embed (partial esum) ----
__global__ __launch_bounds__(256) void finalize_b4(const float* __restrict__ ea_in,
                                                   const float* __restrict__ pesum,
                                                   const float* __restrict__ ncs_slot,
                                                   const float* __restrict__ n_out,
                                                   float* __restrict__ nea_slot,
                                                   float* __restrict__ ne_slot) {
  const int k = blockIdx.x * 256 + threadIdx.x;  // 131072
  const float n = *n_out;
  const size_t P = (size_t)DIM * NE;
  float es = (pesum[k] + pesum[P + k]) + (pesum[2 * P + k] + pesum[3 * P + k]);
  float nea = DECAYF * ea_in[k] + OMDF * es;
  nea_slot[k] = nea;
  float ncs = ncs_slot[k & (NE - 1)];
  float cs = (ncs + EPSF) / (n + NEPSF) * n;
  ne_slot[k] = nea / cs;
}

// ================= small-workspace fallback path (r10, proven) ==========
#define BRF 128
#define TCF 128
#define NTF (NE / TCF)
__global__ __launch_bounds__(256, 2) void argmin_lds_kernel(const float* __restrict__ x,
                                                            const float* __restrict__ E,
                                                            const float* __restrict__ se,
                                                            int* __restrict__ ind,
                                                            float* __restrict__ ind_f) {
  __shared__ float Xs[DIM][BRF];
  __shared__ float Es[DIM][TCF];
  const int tid = threadIdx.x;
  const int rg = tid >> 4;
  const int cg = tid & 15;
  const int B0 = blockIdx.x * BRF;
  const float* xb = x + (size_t)(B0 >> 12) * (DIM * HW) + (B0 & 4095);
  float* Xf = &Xs[0][0];
#pragma unroll
  for (int k = 0; k < 8; ++k) {
    int i = k * 1024 + tid * 4;
    *(float4*)(Xf + i) = *(const float4*)(xb + (i >> 7) * HW + (i & 127));
  }
  float bv[8];
  int bi[8];
#pragma unroll
  for (int i2 = 0; i2 < 8; ++i2) { bv[i2] = 3.4e38f; bi[i2] = 0; }
  float* Ef = &Es[0][0];
  for (int t = 0; t < NTF; ++t) {
    __syncthreads();
#pragma unroll
    for (int k = 0; k < 8; ++k) {
      int i = k * 1024 + tid * 4;
      *(float4*)(Ef + i) = *(const float4*)(E + (i >> 7) * NE + t * TCF + (i & 127));
    }
    __syncthreads();
    float acc[8][8];
#pragma unroll
    for (int i2 = 0; i2 < 8; ++i2)
#pragma unroll
      for (int j = 0; j < 8; ++j) acc[i2][j] = 0.f;
#pragma unroll 8
    for (int d = 0; d < DIM; ++d) {
      float4 xa = *(const float4*)&Xs[d][rg * 8];
      float4 xc = *(const float4*)&Xs[d][rg * 8 + 4];
      float4 ea = *(const float4*)&Es[d][cg * 4];
      float4 ec = *(const float4*)&Es[d][cg * 4 + 64];
      float xr[8] = {xa.x, xa.y, xa.z, xa.w, xc.x, xc.y, xc.z, xc.w};
      float er[8] = {ea.x, ea.y, ea.z, ea.w, ec.x, ec.y, ec.z, ec.w};
#pragma unroll
      for (int i2 = 0; i2 < 8; ++i2)
#pragma unroll
        for (int j = 0; j < 8; ++j) acc[i2][j] = fmaf(xr[i2], er[j], acc[i2][j]);
    }
    float4 s0 = *(const float4*)(se + t * TCF + cg * 4);
    float4 s1 = *(const float4*)(se + t * TCF + cg * 4 + 64);
    float sv[8] = {s0.x, s0.y, s0.z, s0.w, s1.x, s1.y, s1.z, s1.w};
#pragma unroll
    for (int i2 = 0; i2 < 8; ++i2) {
#pragma unroll
      for (int j = 0; j < 8; ++j) {
        float dist = fmaf(-2.f, acc[i2][j], sv[j]);
        if (dist < bv[i2]) {
          bv[i2] = dist;
          bi[i2] = t * TCF + (j >> 2) * 64 + cg * 4 + (j & 3);
        }
      }
    }
  }
#pragma unroll
  for (int i2 = 0; i2 < 8; ++i2) {
    float v = bv[i2];
    int ix = bi[i2];
#pragma unroll
    for (int off = 1; off < 16; off <<= 1) {
      float ov = __shfl_xor(v, off, 64);
      int oi = __shfl_xor(ix, off, 64);
      if (ov < v || (ov == v && oi < ix)) { v = ov; ix = oi; }
    }
    bv[i2] = v;
    bi[i2] = ix;
  }
  if (cg == 0) {
#pragma unroll
    for (int i2 = 0; i2 < 8; ++i2) {
      int grow = B0 + rg * 8 + i2;
      ind[grow] = bi[i2];
      ind_f[grow] = (float)bi[i2];
    }
  }
}

__global__ __launch_bounds__(256) void outdiff_kernel(const float* __restrict__ x,
                                                      const float* __restrict__ E,
                                                      const int* __restrict__ ind,
                                                      float* __restrict__ out,
                                                      float* __restrict__ diff_acc) {
  const int t = threadIdx.x;
  float local = 0.f;
  const int base = blockIdx.x * 1024;
#pragma unroll
  for (int u = 0; u < 4; ++u) {
    int i = base + u * 256 + t;
    int hw = i & 4095;
    int bc = i >> 12;
    int c = bc & 63;
    int b = bc >> 6;
    int idx = ind[b * 4096 + hw];
    float xv = x[i];
    float qv = E[c * NE + idx];
    float dq = qv - xv;
    out[i] = xv + dq;
    local += dq * dq;
  }
#pragma unroll
  for (int off = 32; off > 0; off >>= 1) local += __shfl_down(local, off, 64);
  __shared__ float wsum[4];
  if ((t & 63) == 0) wsum[t >> 6] = local;
  __syncthreads();
  if (t == 0) {
    float s = wsum[0] + wsum[1] + wsum[2] + wsum[3];
    atomicAdd(diff_acc, s * (1.f / 4194304.f));
  }
}

__global__ __launch_bounds__(256) void scatter_atomic_kernel(const float* __restrict__ x,
                                                             const int* __restrict__ ind,
                                                             float* __restrict__ counts,
                                                             float* __restrict__ esum) {
  const int row = blockIdx.x * 256 + threadIdx.x;
  const int idx = ind[row];
  atomicAdd(&counts[idx], 1.f);
  const int b = row >> 12;
  const int hw = row & 4095;
  const float* xr = x + (size_t)b * (DIM * HW) + hw;
#pragma unroll
  for (int d = 0; d < DIM; ++d) atomicAdd(&esum[d * NE + idx], xr[d * HW]);
}

__global__ __launch_bounds__(1024) void finalize_a_float(const float* __restrict__ cs_in,
                                                         float* __restrict__ ncs_slot,
                                                         float* __restrict__ n_out) {
  const int t = threadIdx.x;
  float local = 0.f;
#pragma unroll
  for (int u = 0; u < 2; ++u) {
    int k = u * 1024 + t;
    float v = DECAYF * cs_in[k] + OMDF * ncs_slot[k];
    ncs_slot[k] = v;
    local += v;
  }
#pragma unroll
  for (int off = 32; off > 0; off >>= 1) local += __shfl_down(local, off, 64);
  __shared__ float red[16];
  if ((t & 63) == 0) red[t >> 6] = local;
  __syncthreads();
  if (t == 0) {
    float s = 0.f;
#pragma unroll
    for (int k = 0; k < 16; ++k) s += red[k];
    *n_out = s;
  }
}

__global__ __launch_bounds__(256) void finalize_b_inplace(const float* __restrict__ ea_in,
                                                          float* __restrict__ nea_slot,
                                                          const float* __restrict__ ncs_slot,
                                                          const float* __restrict__ n_out,
                                                          float* __restrict__ ne_slot) {
  const int k = blockIdx.x * 256 + threadIdx.x;
  const float n = *n_out;
  float nea = DECAYF * ea_in[k] + OMDF * nea_slot[k];
  nea_slot[k] = nea;
  float ncs = ncs_slot[k & (NE - 1)];
  float cs = (ncs + EPSF) / (n + NEPSF) * n;
  ne_slot[k] = nea / cs;
}

extern "C" void kernel_launch(void* const* d_in, const int* in_sizes, int n_in,
                              void* d_out, int out_size, void* d_ws, size_t ws_size,
                              hipStream_t stream) {
  const float* x = (const float*)d_in[0];      // [16,64,64,64]
  const float* E = (const float*)d_in[1];      // [64,2048]
  const float* cs_in = (const float*)d_in[2];  // [2048]
  const float* ea_in = (const float*)d_in[3];  // [64,2048]
  float* out = (float*)d_out;

  const size_t O_OUT = 0;
  const size_t O_DIFF = 4194304;
  const size_t O_IND = 4194305;
  const size_t O_NE = 4259841;    // new_embed [64,2048]
  const size_t O_NCS = 4390913;   // new_cluster_size [2048]
  const size_t O_NEA = 4392961;   // new_embed_avg [64,2048]

  // workspace layout
  float* se = (float*)d_ws;                  // 2048
  int* ind = (int*)(se + NE);                // 65536
  float* n_out = (float*)(ind + NROWS);      // 1 (+3 pad)
  int* pcnt = (int*)(n_out + 4);             // 4*2048
  float* pesum = (float*)(pcnt + 4 * NE);    // 4*131072
  // Epk overlays pesum (dead until esum_fused writes it, after argmin)
  _Float16* Ehpk = (_Float16*)pesum;         // 131072 f16 = 256 KB
  _Float16* Elpk = Ehpk + (size_t)DIM * NE;  // 131072 f16
  const size_t need = (size_t)((char*)(pesum + 4 * (size_t)DIM * NE) - (char*)d_ws);
  const bool big_ws = ws_size >= need;

  hipMemsetAsync(out + O_DIFF, 0, 4, stream);

  if (big_ws) {
    prep_kernel<<<72, 256, 0, stream>>>(E, Ehpk, Elpk, se);
    argmin_mfma_kernel<<<NROWS / 128, 256, 0, stream>>>(x, Ehpk, Elpk, se, ind,
                                                        out + O_IND);
    esum_fused_kernel<<<DIM * 4, 256, 0, stream>>>(x, E, ind, out + O_OUT,
                                                   out + O_DIFF, pesum, pcnt);
    finalize_a4<<<1, 1024, 0, stream>>>(cs_in, pcnt, out + O_NCS, n_out);
    finalize_b4<<<DIM * NE / 256, 256, 0, stream>>>(ea_in, pesum, out + O_NCS, n_out,
                                                    out + O_NEA, out + O_NE);
  } else {
    prep_kernel<<<72, 256, 0, stream>>>(E, Ehpk, Elpk, se);  // se still needed
    argmin_lds_kernel<<<NROWS / BRF, 256, 0, stream>>>(x, E, se, ind, out + O_IND);
    outdiff_kernel<<<4096, 256, 0, stream>>>(x, E, ind, out + O_OUT, out + O_DIFF);
    hipMemsetAsync(out + O_NCS, 0, NE * 4, stream);
    hipMemsetAsync(out + O_NEA, 0, (size_t)DIM * NE * 4, stream);
    scatter_atomic_kernel<<<NROWS / 256, 256, 0, stream>>>(x, ind, out + O_NCS,
                                                           out + O_NEA);
    finalize_a_float<<<1, 1024, 0, stream>>>(cs_in, out + O_NCS, n_out);
    finalize_b_inplace<<<DIM * NE / 256, 256, 0, stream>>>(ea_in, out + O_NEA,
                                                           out + O_NCS, n_out,
                                                           out + O_NE);
  }
}